// Round 5
// baseline (244.354 us; speedup 1.0000x reference)
//
#include <hip/hip_runtime.h>
#include <math.h>

#define BB 16
#define HH 128
#define WW 128
#define SNN 10
#define ITERS 8    // truncated Sinkhorn: absmax 0.0 @16 and @32; eps=1 costs are
                   // near-hard-assignment (fast converge) or near-stationary. tol=14.56.

#define NSLOT 64   // contention-spread accumulator slots, one 64B line each
#define NWAVES 4096

typedef float f2 __attribute__((ext_vector_type(2)));

__device__ __forceinline__ float frcp(float x) { return __builtin_amdgcn_rcpf(x); }

// ws layout: acc[slot*16 + k] for slot<64 (k: 0=n_neg 1=n_pos 2=ssq_neg 3=ssq_posneg
// 4=loss_pos_sum), then a u32 completion counter at float index 1024.
// R3->R4 lesson: same-address atomics serialize; 64 lines removed a ~190us tail.
// R5: last-done wave finalizes in-kernel (removes 3rd dispatch + graph gap).
__global__ __launch_bounds__(256) void sinkhorn_loss_kernel(
    const float* __restrict__ outp_g, const float* __restrict__ tgt_g,
    const float* __restrict__ msk_g, float* __restrict__ acc,
    unsigned int* __restrict__ cnt, float* __restrict__ res)
{
    const int HW = HH * WW;
    int p  = blockIdx.x * 256 + threadIdx.x;   // 0..262143
    int b  = p >> 14;
    int hw = p & (HW - 1);
    int h  = hw >> 7;
    int w  = hw & 127;
    float hf = (float)h, wf = (float)w;

    const float* outp = outp_g + (size_t)b * 36 * HW + hw;
    const float* tgtp = tgt_g  + (size_t)b * 20 * HW + hw;

    // ---- out channels: ssq_all (all 36 ch), predicted coords, neg-anchor ssq ----
    float ssq_all = 0.f, ssq_pn = 0.f;
    float ox[10], oy[10];
    #pragma unroll
    for (int j = 0; j < 9; j++) {            // head0 x: ch 0..8
        float v = outp[j * HW];
        ssq_all += v * v;
        ox[j] = v + (float)(j / 3 - 1) + hf;
    }
    #pragma unroll
    for (int j = 0; j < 9; j++) {            // head0 y: ch 9..17
        float v = outp[(9 + j) * HW];
        ssq_all += v * v;
        oy[j] = v + (float)(j % 3 - 1) + wf;
    }
    {                                         // head1 x idx0: ch 18
        float v = outp[18 * HW];
        ssq_all += v * v;
        ox[9] = v - 1.f + hf;
    }
    #pragma unroll
    for (int idx = 1; idx < 9; idx++) {       // head1 x idx 1..8 (o2_neg x)
        float v = outp[(18 + idx) * HW];
        ssq_all += v * v;
        float t = v + (float)(idx / 3 - 1) + hf;
        ssq_pn += t * t;
    }
    {                                         // head1 y idx0: ch 27
        float v = outp[27 * HW];
        ssq_all += v * v;
        oy[9] = v - 1.f + wf;
    }
    #pragma unroll
    for (int idx = 1; idx < 9; idx++) {       // head1 y idx 1..8 (o2_neg y)
        float v = outp[(27 + idx) * HW];
        ssq_all += v * v;
        float t = v + (float)(idx % 3 - 1) + wf;
        ssq_pn += t * t;
    }

    // ---- cost -> K = exp(cmin - cost), rows packed as float2 pairs along j ----
    // (global shift by cmin is exactly assignment-invariant; keeps K in (e^-40, 1])
    f2 Km[SNN][5];
    float cmin = 1e30f;
    #pragma unroll
    for (int i = 0; i < SNN; i++) {
        float tx = tgtp[i * HW];
        float ty = tgtp[(10 + i) * HW];
        #pragma unroll
        for (int jj = 0; jj < 5; jj++) {
            float c0 = fabsf(tx - ox[2*jj])   + fabsf(ty - oy[2*jj]);
            float c1 = fabsf(tx - ox[2*jj+1]) + fabsf(ty - oy[2*jj+1]);
            Km[i][jj].x = c0;
            Km[i][jj].y = c1;
            cmin = fminf(cmin, fminf(c0, c1));
        }
    }
    #pragma unroll
    for (int i = 0; i < SNN; i++)
        #pragma unroll
        for (int jj = 0; jj < 5; jj++) {
            Km[i][jj].x = __expf(cmin - Km[i][jj].x);
            Km[i][jj].y = __expf(cmin - Km[i][jj].y);
        }

    // ---- scale-free Sinkhorn: a = 1/(K b), b = 1/(K^T a); assignment = K a b ----
    f2 b2[5];
    float av[SNN];
    #pragma unroll
    for (int jj = 0; jj < 5; jj++) { b2[jj].x = 1.f; b2[jj].y = 1.f; }

    #pragma unroll 1
    for (int it = 0; it < ITERS; ++it) {
        #pragma unroll
        for (int i = 0; i < SNN; i++) {
            f2 s = Km[i][0] * b2[0];
            #pragma unroll
            for (int jj = 1; jj < 5; jj++) s += Km[i][jj] * b2[jj];
            av[i] = frcp(s.x + s.y);
        }
        f2 c2[5];
        #pragma unroll
        for (int jj = 0; jj < 5; jj++) c2[jj] = Km[0][jj] * av[0];
        #pragma unroll
        for (int i = 1; i < SNN; i++) {
            #pragma unroll
            for (int jj = 0; jj < 5; jj++) c2[jj] += Km[i][jj] * av[i];
        }
        #pragma unroll
        for (int jj = 0; jj < 5; jj++) {
            b2[jj].x = frcp(c2[jj].x);
            b2[jj].y = frcp(c2[jj].y);
        }
    }

    // ---- epilogue: lp = Σ_ij m_i · (K a b) · cost, cost = cmin - ln(K) ----
    const float* mkp = msk_g + (size_t)b * 10 * HW + hw;
    float msum = 0.f, lp = 0.f;
    #pragma unroll
    for (int i = 0; i < SNN; i++) {
        float s = 0.f;
        #pragma unroll
        for (int jj = 0; jj < 5; jj++) {
            float kx = Km[i][jj].x, ky = Km[i][jj].y;
            float cx = cmin - __logf(fmaxf(kx, 1e-37f));
            float cy = cmin - __logf(fmaxf(ky, 1e-37f));
            s += kx * b2[jj].x * cx;
            s += ky * b2[jj].y * cy;
        }
        float mi = mkp[i * HW];
        msum += mi;
        lp += mi * av[i] * s;
    }
    float pos = (msum >= 1.f) ? 1.f : 0.f;
    float neg = 1.f - pos;
    lp = (msum >= 1.f) ? lp : 0.f;

    // ---- wave shfl-reduction + 5 atomics per wave into this wave's slot line ----
    float vals[5];
    vals[0] = neg;
    vals[1] = pos;
    vals[2] = ssq_all * neg;
    vals[3] = ssq_pn * pos;
    vals[4] = lp;
    int lane = threadIdx.x & 63;
    int waveId = (blockIdx.x << 2) | (threadIdx.x >> 6);
    float* line = acc + (waveId & (NSLOT - 1)) * 16;
    #pragma unroll
    for (int k = 0; k < 5; k++) {
        float v = vals[k];
        #pragma unroll
        for (int off = 32; off > 0; off >>= 1) v += __shfl_down(v, off);
        if (lane == 0) atomicAdd(&line[k], v);
    }

    // ---- last-done wave finalizes (no 3rd dispatch) ----
    __threadfence();                           // order slot atomics before counter
    unsigned int old = 0;
    if (lane == 0) old = atomicAdd(cnt, 1u);
    old = __shfl(old, 0);
    if (old == NWAVES - 1) {
        __threadfence();
        // device-scope atomic reads: coherent across XCD L2s
        float v0 = atomicAdd(&acc[lane * 16 + 0], 0.f);
        float v1 = atomicAdd(&acc[lane * 16 + 1], 0.f);
        float v2 = atomicAdd(&acc[lane * 16 + 2], 0.f);
        float v3 = atomicAdd(&acc[lane * 16 + 3], 0.f);
        float v4 = atomicAdd(&acc[lane * 16 + 4], 0.f);
        #pragma unroll
        for (int off = 32; off > 0; off >>= 1) {
            v0 += __shfl_down(v0, off);
            v1 += __shfl_down(v1, off);
            v2 += __shfl_down(v2, off);
            v3 += __shfl_down(v3, off);
            v4 += __shfl_down(v4, off);
        }
        if (lane == 0) {
            float loss_neg     = sqrtf(v2) / v0;
            float loss_pos_neg = sqrtf(v3) / v1;
            res[0] = (loss_neg + loss_pos_neg) * 100.f + v4 / (v1 + 0.0001f);
        }
    }
}

extern "C" void kernel_launch(void* const* d_in, const int* in_sizes, int n_in,
                              void* d_out, int out_size, void* d_ws, size_t ws_size,
                              hipStream_t stream) {
    const float* outp = (const float*)d_in[0];
    const float* tgt  = (const float*)d_in[1];
    const float* msk  = (const float*)d_in[2];
    float* acc = (float*)d_ws;
    unsigned int* cnt = (unsigned int*)((float*)d_ws + NSLOT * 16);
    float* res = (float*)d_out;

    // zero 64 slot-lines + counter line
    hipMemsetAsync(d_ws, 0, (NSLOT * 16 + 16) * sizeof(float), stream);

    const int total = BB * HH * WW;           // 262144
    dim3 block(256);
    dim3 grid(total / 256);                   // 1024 blocks = 4096 waves
    sinkhorn_loss_kernel<<<grid, block, 0, stream>>>(outp, tgt, msk, acc, cnt, res);
}

// Round 6
// 123.200 us; speedup vs baseline: 1.9834x; 1.9834x over previous
//
#include <hip/hip_runtime.h>
#include <math.h>

#define BB 16
#define HH 128
#define WW 128
#define SNN 10
#define ITERS 8    // validated: absmax 0.0 @8 (R5), @16 (R3/R4), @32 (R2). tol=14.56.

#define NSLOT 64   // contention-spread accumulator slots, one 64B line each

typedef float f2 __attribute__((ext_vector_type(2)));

__device__ __forceinline__ float frcp(float x) { return __builtin_amdgcn_rcpf(x); }

// acc layout: acc[slot*16 + k], k: 0=n_neg 1=n_pos 2=ssq_neg 3=ssq_posneg 4=loss_pos.
// R4 lesson: 64 slot-lines de-contend atomics (4096-deep chains -> 64) = -190us tail.
// R5 lesson: fused last-wave finalize REGRESSED +85us — per-wave __threadfence() +
// single-address counter atomic across 4096 waves. Keep the separate tiny finalize.
__global__ __launch_bounds__(256) void sinkhorn_loss_kernel(
    const float* __restrict__ outp_g, const float* __restrict__ tgt_g,
    const float* __restrict__ msk_g, float* __restrict__ acc)
{
    const int HW = HH * WW;
    int p  = blockIdx.x * 256 + threadIdx.x;   // 0..262143
    int b  = p >> 14;
    int hw = p & (HW - 1);
    int h  = hw >> 7;
    int w  = hw & 127;
    float hf = (float)h, wf = (float)w;

    const float* outp = outp_g + (size_t)b * 36 * HW + hw;
    const float* tgtp = tgt_g  + (size_t)b * 20 * HW + hw;

    // ---- out channels: ssq_all (all 36 ch), predicted coords, neg-anchor ssq ----
    float ssq_all = 0.f, ssq_pn = 0.f;
    float ox[10], oy[10];
    #pragma unroll
    for (int j = 0; j < 9; j++) {            // head0 x: ch 0..8
        float v = outp[j * HW];
        ssq_all += v * v;
        ox[j] = v + (float)(j / 3 - 1) + hf;
    }
    #pragma unroll
    for (int j = 0; j < 9; j++) {            // head0 y: ch 9..17
        float v = outp[(9 + j) * HW];
        ssq_all += v * v;
        oy[j] = v + (float)(j % 3 - 1) + wf;
    }
    {                                         // head1 x idx0: ch 18
        float v = outp[18 * HW];
        ssq_all += v * v;
        ox[9] = v - 1.f + hf;
    }
    #pragma unroll
    for (int idx = 1; idx < 9; idx++) {       // head1 x idx 1..8 (o2_neg x)
        float v = outp[(18 + idx) * HW];
        ssq_all += v * v;
        float t = v + (float)(idx / 3 - 1) + hf;
        ssq_pn += t * t;
    }
    {                                         // head1 y idx0: ch 27
        float v = outp[27 * HW];
        ssq_all += v * v;
        oy[9] = v - 1.f + wf;
    }
    #pragma unroll
    for (int idx = 1; idx < 9; idx++) {       // head1 y idx 1..8 (o2_neg y)
        float v = outp[(27 + idx) * HW];
        ssq_all += v * v;
        float t = v + (float)(idx % 3 - 1) + wf;
        ssq_pn += t * t;
    }

    // ---- cost -> K = exp(cmin - cost), rows packed as float2 pairs along j ----
    // (global shift by cmin is exactly assignment-invariant; keeps K in (e^-40, 1])
    f2 Km[SNN][5];
    float cmin = 1e30f;
    #pragma unroll
    for (int i = 0; i < SNN; i++) {
        float tx = tgtp[i * HW];
        float ty = tgtp[(10 + i) * HW];
        #pragma unroll
        for (int jj = 0; jj < 5; jj++) {
            float c0 = fabsf(tx - ox[2*jj])   + fabsf(ty - oy[2*jj]);
            float c1 = fabsf(tx - ox[2*jj+1]) + fabsf(ty - oy[2*jj+1]);
            Km[i][jj].x = c0;
            Km[i][jj].y = c1;
            cmin = fminf(cmin, fminf(c0, c1));
        }
    }
    #pragma unroll
    for (int i = 0; i < SNN; i++)
        #pragma unroll
        for (int jj = 0; jj < 5; jj++) {
            Km[i][jj].x = __expf(cmin - Km[i][jj].x);
            Km[i][jj].y = __expf(cmin - Km[i][jj].y);
        }

    // ---- scale-free Sinkhorn: a = 1/(K b), b = 1/(K^T a); assignment = K a b ----
    f2 b2[5];
    float av[SNN];
    #pragma unroll
    for (int jj = 0; jj < 5; jj++) { b2[jj].x = 1.f; b2[jj].y = 1.f; }

    #pragma unroll 1
    for (int it = 0; it < ITERS; ++it) {
        #pragma unroll
        for (int i = 0; i < SNN; i++) {
            f2 s = Km[i][0] * b2[0];
            #pragma unroll
            for (int jj = 1; jj < 5; jj++) s += Km[i][jj] * b2[jj];
            av[i] = frcp(s.x + s.y);
        }
        f2 c2[5];
        #pragma unroll
        for (int jj = 0; jj < 5; jj++) c2[jj] = Km[0][jj] * av[0];
        #pragma unroll
        for (int i = 1; i < SNN; i++) {
            #pragma unroll
            for (int jj = 0; jj < 5; jj++) c2[jj] += Km[i][jj] * av[i];
        }
        #pragma unroll
        for (int jj = 0; jj < 5; jj++) {
            b2[jj].x = frcp(c2[jj].x);
            b2[jj].y = frcp(c2[jj].y);
        }
    }

    // ---- epilogue: lp = Σ_ij m_i · (K a b) · cost, cost = cmin - ln(K) ----
    const float* mkp = msk_g + (size_t)b * 10 * HW + hw;
    float msum = 0.f, lp = 0.f;
    #pragma unroll
    for (int i = 0; i < SNN; i++) {
        float s = 0.f;
        #pragma unroll
        for (int jj = 0; jj < 5; jj++) {
            float kx = Km[i][jj].x, ky = Km[i][jj].y;
            float cx = cmin - __logf(fmaxf(kx, 1e-37f));
            float cy = cmin - __logf(fmaxf(ky, 1e-37f));
            s += kx * b2[jj].x * cx;
            s += ky * b2[jj].y * cy;
        }
        float mi = mkp[i * HW];
        msum += mi;
        lp += mi * av[i] * s;
    }
    float pos = (msum >= 1.f) ? 1.f : 0.f;
    float neg = 1.f - pos;
    lp = (msum >= 1.f) ? lp : 0.f;

    // ---- wave shfl-reduction + 5 atomics per wave into this wave's slot line ----
    float vals[5];
    vals[0] = neg;
    vals[1] = pos;
    vals[2] = ssq_all * neg;
    vals[3] = ssq_pn * pos;
    vals[4] = lp;
    int waveId = (blockIdx.x << 2) | (threadIdx.x >> 6);
    float* line = acc + (waveId & (NSLOT - 1)) * 16;
    #pragma unroll
    for (int k = 0; k < 5; k++) {
        float v = vals[k];
        #pragma unroll
        for (int off = 32; off > 0; off >>= 1) v += __shfl_down(v, off);
        if ((threadIdx.x & 63) == 0) atomicAdd(&line[k], v);
    }
}

__global__ void finalize_kernel(const float* __restrict__ acc, float* __restrict__ out)
{
    int lane = threadIdx.x;            // one wave of 64 = NSLOT
    float v0 = acc[lane * 16 + 0];
    float v1 = acc[lane * 16 + 1];
    float v2 = acc[lane * 16 + 2];
    float v3 = acc[lane * 16 + 3];
    float v4 = acc[lane * 16 + 4];
    #pragma unroll
    for (int off = 32; off > 0; off >>= 1) {
        v0 += __shfl_down(v0, off);
        v1 += __shfl_down(v1, off);
        v2 += __shfl_down(v2, off);
        v3 += __shfl_down(v3, off);
        v4 += __shfl_down(v4, off);
    }
    if (lane == 0) {
        float loss_neg     = sqrtf(v2) / v0;
        float loss_pos_neg = sqrtf(v3) / v1;
        out[0] = (loss_neg + loss_pos_neg) * 100.f + v4 / (v1 + 0.0001f);
    }
}

extern "C" void kernel_launch(void* const* d_in, const int* in_sizes, int n_in,
                              void* d_out, int out_size, void* d_ws, size_t ws_size,
                              hipStream_t stream) {
    const float* outp = (const float*)d_in[0];
    const float* tgt  = (const float*)d_in[1];
    const float* msk  = (const float*)d_in[2];
    float* acc = (float*)d_ws;
    float* res = (float*)d_out;

    hipMemsetAsync(acc, 0, NSLOT * 16 * sizeof(float), stream);

    const int total = BB * HH * WW;           // 262144
    dim3 block(256);
    dim3 grid(total / 256);                   // 1024 blocks = 4096 waves
    sinkhorn_loss_kernel<<<grid, block, 0, stream>>>(outp, tgt, msk, acc);
    finalize_kernel<<<1, 64, 0, stream>>>(acc, res);
}